// Round 3
// baseline (837.287 us; speedup 1.0000x reference)
//
#include <hip/hip_runtime.h>

// EdgeEmbAttentionAggregator: fused GAT-style aggregation. FLOAT32 I/O.
// Algebra: neighs@a_n = neigh_feat@(W2@a_n); h_prime = agg@W2 where
// agg = sum_s att[s]*neigh_feat[n,s,:].
//
// R2 (resubmit R3; R2 bench failed on GPU acquisition — no counters):
// DS-pipe vectorization + structural fusion (theory: kernel was LDS
// issue-bound on ~420 scalar b32 wave-DS-instrs/node).
//  - all LDS reads ds_read_b128 (float4): A/E broadcasts 32->8, B rows
//    contiguous 256B chunks, D columns as 32-lane contiguous 512B reads
//  - staging via global_load_lds width=16 into unpadded double-buffered
//    tile (wave 3 issues 12 DMA instrs; vmcnt(0) drained only by wave 3,
//    once per iteration, just before the closing barrier)
//  - C(softmax)+D(aggregate) fused in wave 0 (wave-internal lgkmcnt +
//    sched_barrier between s_att write and read; no block barrier)
//  - barriers per node: 4 -> 3, all lgkmcnt-only (no vmcnt drain)

#define BAR() do {                                              \
    asm volatile("s_waitcnt lgkmcnt(0)" ::: "memory");          \
    __builtin_amdgcn_s_barrier();                               \
    asm volatile("" ::: "memory");                              \
} while (0)

#define GLDS16(gp, lp) __builtin_amdgcn_global_load_lds(                     \
    (const __attribute__((address_space(1))) void*)(gp),                     \
    (__attribute__((address_space(3))) void*)(lp), 16, 0, 0)
#define GLDS4(gp, lp)  __builtin_amdgcn_global_load_lds(                     \
    (const __attribute__((address_space(1))) void*)(gp),                     \
    (__attribute__((address_space(3))) void*)(lp), 4, 0, 0)

__device__ __forceinline__ float dot4(float4 a, float4 b) {
    return fmaf(a.x, b.x, fmaf(a.y, b.y, fmaf(a.z, b.z, a.w * b.w)));
}

// ws layout (fp32): [0:128) w2a = W2 @ a_n ; [128:288) copy of a[0:160)
__global__ __launch_bounds__(256)
void prep_kernel(const float* __restrict__ W2,
                 const float* __restrict__ a,
                 float* __restrict__ ws) {
    const int t = threadIdx.x;
    __shared__ float s_a[160];
    if (t < 160) { float v = a[t]; s_a[t] = v; ws[128 + t] = v; }
    __syncthreads();
    if (t < 128) {
        float p = 0.f;
        #pragma unroll
        for (int d = 0; d < 64; d++) p = fmaf(W2[t * 64 + d], s_a[64 + d], p);
        ws[t] = p;
    }
}

__global__ __launch_bounds__(256, 4)
void gat_kernel(const float* __restrict__ input,
                const float* __restrict__ neigh,
                const float* __restrict__ edge,
                const float* __restrict__ W,
                const float* __restrict__ W2,
                const float* __restrict__ ws,
                float* __restrict__ out,
                int N) {
    const int t = threadIdx.x;
    const int d = t & 63;        // output column (x / h')
    const int q = t >> 6;        // wave id = K-quarter
    const int lane = t & 63;

    __shared__ float s_ws[288];
    __shared__ float s_in[2][128];
    __shared__ float s_ng[2][2048];   // 16 x 128, unpadded (DMA-contiguous)
    __shared__ float s_ee[2][512];    // 16 x 32, unpadded
    __shared__ float s_redA[256];
    __shared__ float s_redE[256];
    __shared__ float s_agg[128];
    __shared__ float s_sc[16];
    __shared__ float s_att[16];

    // block-invariant: W/W2 K-quarter columns into registers
    float rW[32], rW2[32];
    {
        const int kb = q * 32;
        #pragma unroll
        for (int k = 0; k < 32; k++) {
            rW[k]  = W [(kb + k) * 64 + d];
            rW2[k] = W2[(kb + k) * 64 + d];
        }
    }
    s_ws[t] = ws[t];
    if (t < 32) s_ws[256 + t] = ws[256 + t];

    const int stride = gridDim.x;
    int n = blockIdx.x;
    int n_prev = -1;
    int cur = 0;

    // ---- prologue: wave 3 DMAs node n into buf 0, drains, barrier
    if (q == 3) {
        const float* gn = neigh + (size_t)n * 2048;
        #pragma unroll
        for (int i = 0; i < 8; i++) GLDS16(gn + i * 256 + lane * 4, &s_ng[0][i * 256]);
        const float* ge = edge + (size_t)n * 512;
        #pragma unroll
        for (int i = 0; i < 2; i++) GLDS16(ge + i * 256 + lane * 4, &s_ee[0][i * 256]);
        const float* gi = input + (size_t)n * 128;
        #pragma unroll
        for (int i = 0; i < 2; i++) GLDS4(gi + i * 64 + lane, &s_in[0][i * 64]);
        asm volatile("s_waitcnt vmcnt(0)" ::: "memory");
    }
    BAR();

    for (; n < N; n += stride, cur ^= 1) {
        // ---- wave 3: issue DMA for next node into cur^1 (drained at BAR3)
        const int nn = n + stride;
        if (q == 3 && nn < N) {
            const float* gn = neigh + (size_t)nn * 2048;
            #pragma unroll
            for (int i = 0; i < 8; i++) GLDS16(gn + i * 256 + lane * 4, &s_ng[cur ^ 1][i * 256]);
            const float* ge = edge + (size_t)nn * 512;
            #pragma unroll
            for (int i = 0; i < 2; i++) GLDS16(ge + i * 256 + lane * 4, &s_ee[cur ^ 1][i * 256]);
            const float* gi = input + (size_t)nn * 128;
            #pragma unroll
            for (int i = 0; i < 2; i++) GLDS4(gi + i * 64 + lane, &s_in[cur ^ 1][i * 64]);
        }

        // ---- Phase A: x[d] K-quarter partial, vectorized broadcast reads
        {
            const float4* in4 = (const float4*)s_in[cur];
            float p = 0.f;
            #pragma unroll
            for (int j = 0; j < 8; j++) {
                const float4 v = in4[q * 8 + j];
                p = fmaf(v.x, rW[4 * j + 0], p);
                p = fmaf(v.y, rW[4 * j + 1], p);
                p = fmaf(v.z, rW[4 * j + 2], p);
                p = fmaf(v.w, rW[4 * j + 3], p);
            }
            s_redA[t] = p;
        }
        // ---- Phase B: score partials, 16 threads/row, float4 chunks
        {
            const int s = t >> 4, g = t & 15;
            const float4* ng4 = (const float4*)(s_ng[cur] + s * 128);
            const float4* wa4 = (const float4*)s_ws;
            float p = dot4(ng4[g], wa4[g]) + dot4(ng4[g + 16], wa4[g + 16]);
            if (g < 8) {
                const float4 e4 = ((const float4*)(s_ee[cur] + s * 32))[g];
                const float4 a4 = ((const float4*)(s_ws + 256))[g];
                p += dot4(e4, a4);
            }
            #pragma unroll
            for (int off = 8; off; off >>= 1) p += __shfl_down(p, off, 16);
            if (g == 0) s_sc[s] = p;
        }
        // ---- Phase F (prev node): finalize h' (wave 0)
        if (q == 0 && n_prev >= 0) {
            out[(size_t)n_prev * 160 + 64 + d] =
                s_redE[d] + s_redE[64 + d] + s_redE[128 + d] + s_redE[192 + d];
        }
        BAR();   // BAR1

        // ---- Phase C+D: wave 0 only (softmax then aggregate, no barrier)
        if (q == 0) {
            const float x = s_redA[d] + s_redA[64 + d] + s_redA[128 + d] + s_redA[192 + d];
            out[(size_t)n * 160 + d] = x;
            float p = x * s_ws[128 + d];              // a_x
            #pragma unroll
            for (int off = 32; off; off >>= 1) p += __shfl_down(p, off, 64);
            const float sx = __shfl(p, 0, 64);
            if (t < 16) {
                const float sc = sx + s_sc[t];
                const float e = sc > 0.f ? sc : 0.8f * sc;
                float m = e;
                #pragma unroll
                for (int off = 8; off; off >>= 1) m = fmaxf(m, __shfl_xor(m, off, 16));
                const float ex = __expf(e - m);
                float sum = ex;
                #pragma unroll
                for (int off = 8; off; off >>= 1) sum += __shfl_xor(sum, off, 16);
                s_att[t] = ex / sum;
            }
            // wave-internal write->read of s_att: force the wait + pin order
            // (rule 18: hipcc can hoist reg-only consumers past asm lgkmcnt)
            asm volatile("s_waitcnt lgkmcnt(0)" ::: "memory");
            __builtin_amdgcn_sched_barrier(0);
            float attv[16];
            #pragma unroll
            for (int j = 0; j < 4; j++) {
                const float4 v = ((const float4*)s_att)[j];
                attv[4 * j + 0] = v.x; attv[4 * j + 1] = v.y;
                attv[4 * j + 2] = v.z; attv[4 * j + 3] = v.w;
            }
            if (t < 32) {
                // agg cols [4t, 4t+4): 32-lane contiguous 512B reads per s
                const float4* col = (const float4*)s_ng[cur] + t;
                float4 acc = make_float4(0.f, 0.f, 0.f, 0.f);
                #pragma unroll
                for (int s = 0; s < 16; s++) {
                    const float4 v = col[s * 32];
                    acc.x = fmaf(attv[s], v.x, acc.x);
                    acc.y = fmaf(attv[s], v.y, acc.y);
                    acc.z = fmaf(attv[s], v.z, acc.z);
                    acc.w = fmaf(attv[s], v.w, acc.w);
                }
                ((float4*)s_agg)[t] = acc;
            } else if (t < 40) {
                const int e = t - 32;
                const float4* col = (const float4*)s_ee[cur] + e;
                float4 acc = make_float4(0.f, 0.f, 0.f, 0.f);
                #pragma unroll
                for (int s = 0; s < 16; s++) {
                    const float4 v = col[s * 8];
                    acc.x = fmaf(attv[s], v.x, acc.x);
                    acc.y = fmaf(attv[s], v.y, acc.y);
                    acc.z = fmaf(attv[s], v.z, acc.z);
                    acc.w = fmaf(attv[s], v.w, acc.w);
                }
                *(float4*)(out + (size_t)n * 160 + 128 + 4 * e) = acc;
            }
        }
        BAR();   // BAR2

        // ---- Phase E: h'[d] K-quarter partial from s_agg (broadcast b128)
        {
            const float4* ag4 = (const float4*)s_agg;
            float p = 0.f;
            #pragma unroll
            for (int j = 0; j < 8; j++) {
                const float4 v = ag4[q * 8 + j];
                p = fmaf(v.x, rW2[4 * j + 0], p);
                p = fmaf(v.y, rW2[4 * j + 1], p);
                p = fmaf(v.z, rW2[4 * j + 2], p);
                p = fmaf(v.w, rW2[4 * j + 3], p);
            }
            s_redE[t] = p;
        }
        // wave 3: its DMA loads (issued at iteration top) must land before
        // anyone reads cur^1 after this barrier
        if (q == 3) asm volatile("s_waitcnt vmcnt(0)" ::: "memory");
        n_prev = n;
        BAR();   // BAR3
    }

    // ---- epilogue: finalize h' of the last node
    if (q == 0 && n_prev >= 0) {
        out[(size_t)n_prev * 160 + 64 + d] =
            s_redE[d] + s_redE[64 + d] + s_redE[128 + d] + s_redE[192 + d];
    }
}

extern "C" void kernel_launch(void* const* d_in, const int* in_sizes, int n_in,
                              void* d_out, int out_size, void* d_ws, size_t ws_size,
                              hipStream_t stream) {
    const float* input = (const float*)d_in[0];
    const float* neigh = (const float*)d_in[1];
    const float* edge  = (const float*)d_in[2];
    const float* W     = (const float*)d_in[3];
    const float* W2    = (const float*)d_in[4];
    const float* a     = (const float*)d_in[5];
    float* ws = (float*)d_ws;
    float* out = (float*)d_out;

    const int N = in_sizes[0] / 128;   // 50000

    prep_kernel<<<1, 256, 0, stream>>>(W2, a, ws);
    gat_kernel<<<1024, 256, 0, stream>>>(input, neigh, edge, W, W2, ws, out, N);
}

// Round 4
// 692.753 us; speedup vs baseline: 1.2086x; 1.2086x over previous
//
#include <hip/hip_runtime.h>
#include <hip/hip_fp16.h>

// EdgeEmbAttentionAggregator — R4: three-pass, weight-free inner loop.
// Algebra: score_s = in·Wa + ng_s·w2a + ee_s·a_e  (Wa = W@a_x, w2a = W2@a_n)
//   -> softmax never needs x. h' = (att@NG)@W2 = agg@W2 (agg via f16 in out).
// K1 prep: w2a, Wa. K2 attention (no weights, 2 barriers/node, 7 blocks/CU):
//   scores -> in-register redundant softmax -> unified aggregate ->
//   agg(f16, packed into out h' slot) + h_edge(f32). K3 dual-GEMM:
//   x = in@W -> out[:,0:64); h' = agg@W2 -> out[:,64:128) (in-place).

#define BAR() do {                                              \
    asm volatile("s_waitcnt lgkmcnt(0)" ::: "memory");          \
    __builtin_amdgcn_s_barrier();                               \
    asm volatile("" ::: "memory");                              \
} while (0)

#define GLDS16(gp, lp) __builtin_amdgcn_global_load_lds(                     \
    (const __attribute__((address_space(1))) void*)(gp),                     \
    (__attribute__((address_space(3))) void*)(lp), 16, 0, 0)
#define GLDS4(gp, lp)  __builtin_amdgcn_global_load_lds(                     \
    (const __attribute__((address_space(1))) void*)(gp),                     \
    (__attribute__((address_space(3))) void*)(lp), 4, 0, 0)

__device__ __forceinline__ float dot4(float4 a, float4 b) {
    return fmaf(a.x, b.x, fmaf(a.y, b.y, fmaf(a.z, b.z, a.w * b.w)));
}

// ws layout (fp32): [0:128) w2a=W2@a_n ; [128:288) a copy ; [288:416) Wa=W@a_x
__global__ __launch_bounds__(256)
void prep_kernel(const float* __restrict__ W,
                 const float* __restrict__ W2,
                 const float* __restrict__ a,
                 float* __restrict__ ws) {
    const int t = threadIdx.x;
    __shared__ float s_a[160];
    if (t < 160) { float v = a[t]; s_a[t] = v; ws[128 + t] = v; }
    __syncthreads();
    if (t < 128) {
        float p = 0.f, pw = 0.f;
        #pragma unroll
        for (int d = 0; d < 64; d++) {
            p  = fmaf(W2[t * 64 + d], s_a[64 + d], p);
            pw = fmaf(W [t * 64 + d], s_a[d],      pw);
        }
        ws[t] = p;
        ws[288 + t] = pw;
    }
}

__device__ __forceinline__ void dma_node(const float* __restrict__ neigh,
                                         const float* __restrict__ edge,
                                         const float* __restrict__ input,
                                         int node, int lane,
                                         float* ng, float* ee, float* inb) {
    const float* gn = neigh + (size_t)node * 2048;
    #pragma unroll
    for (int i = 0; i < 8; i++) GLDS16(gn + i * 256 + lane * 4, ng + i * 256);
    const float* ge = edge + (size_t)node * 512;
    #pragma unroll
    for (int i = 0; i < 2; i++) GLDS16(ge + i * 256 + lane * 4, ee + i * 256);
    const float* gi = input + (size_t)node * 128;
    #pragma unroll
    for (int i = 0; i < 2; i++) GLDS4(gi + i * 64 + lane, inb + i * 64);
}

__global__ __launch_bounds__(256, 6)
void gat_attn(const float* __restrict__ input,
              const float* __restrict__ neigh,
              const float* __restrict__ edge,
              const float* __restrict__ ws,
              float* __restrict__ out, int N) {
    const int t = threadIdx.x;
    const int q = t >> 6;
    const int lane = t & 63;

    __shared__ __align__(16) float s_w2a[128];
    __shared__ __align__(16) float s_wa[128];
    __shared__ __align__(16) float s_ae[32];
    __shared__ __align__(16) float s_in[2][128];
    __shared__ __align__(16) float s_ng[2][2048];   // 16 x 128
    __shared__ __align__(16) float s_ee[2][512];    // 16 x 32
    __shared__ __align__(16) float s_sc[16];

    if (t < 128) { s_w2a[t] = ws[t]; s_wa[t] = ws[288 + t]; }
    else if (t < 160) s_ae[t - 128] = ws[128 + t];   // ws[256:288) = a_e

    const int stride = gridDim.x;
    int n = blockIdx.x;
    int cur = 0;

    // prologue: wave 3 DMAs node n into buf 0
    if (q == 3 && n < N) {
        dma_node(neigh, edge, input, n, lane, s_ng[0], s_ee[0], s_in[0]);
        asm volatile("s_waitcnt vmcnt(0)" ::: "memory");
    }
    BAR();   // also covers s_w2a/s_wa/s_ae

    for (; n < N; n += stride, cur ^= 1) {
        const int nn = n + stride;
        if (q == 3 && nn < N)
            dma_node(neigh, edge, input, nn, lane,
                     s_ng[cur ^ 1], s_ee[cur ^ 1], s_in[cur ^ 1]);

        // ---- Phase B: complete pre-activation scores (16 threads/row)
        {
            const int s = t >> 4, g = t & 15;
            const float4* ng4  = (const float4*)(s_ng[cur] + s * 128);
            const float4* w2a4 = (const float4*)s_w2a;
            const float4* in4  = (const float4*)s_in[cur];
            const float4* wa4  = (const float4*)s_wa;
            float p = dot4(ng4[g], w2a4[g]) + dot4(ng4[g + 16], w2a4[g + 16])
                    + dot4(in4[g], wa4[g]) + dot4(in4[g + 16], wa4[g + 16]);
            if (g < 8)
                p += dot4(((const float4*)(s_ee[cur] + s * 32))[g],
                          ((const float4*)s_ae)[g]);
            #pragma unroll
            for (int off = 8; off; off >>= 1) p += __shfl_down(p, off, 16);
            if (g == 0) s_sc[s] = p;
        }
        BAR();   // BAR1

        // ---- softmax (redundant, in-register, no cross-lane) + aggregate
        if (q == 0) {
            float e[16];
            #pragma unroll
            for (int j = 0; j < 4; j++) {
                const float4 v = ((const float4*)s_sc)[j];
                e[4*j+0] = v.x > 0.f ? v.x : 0.8f * v.x;
                e[4*j+1] = v.y > 0.f ? v.y : 0.8f * v.y;
                e[4*j+2] = v.z > 0.f ? v.z : 0.8f * v.z;
                e[4*j+3] = v.w > 0.f ? v.w : 0.8f * v.w;
            }
            float m[8];
            #pragma unroll
            for (int i = 0; i < 8; i++) m[i] = fmaxf(e[i], e[i + 8]);
            #pragma unroll
            for (int i = 0; i < 4; i++) m[i] = fmaxf(m[i], m[i + 4]);
            const float mx = fmaxf(fmaxf(m[0], m[2]), fmaxf(m[1], m[3]));
            #pragma unroll
            for (int s = 0; s < 16; s++) e[s] = __expf(e[s] - mx);
            float sm[8];
            #pragma unroll
            for (int i = 0; i < 8; i++) sm[i] = e[i] + e[i + 8];
            #pragma unroll
            for (int i = 0; i < 4; i++) sm[i] = sm[i] + sm[i + 4];
            const float sum = (sm[0] + sm[2]) + (sm[1] + sm[3]);
            const float rinv = 1.0f / sum;   // folded in AFTER the loop

            // unified aggregate: lanes 0-31 -> ng f4-cols, 32-39 -> ee f4-cols
            const bool isng = (t < 32);
            const float4* base = isng ? ((const float4*)s_ng[cur] + t)
                                      : ((const float4*)s_ee[cur] + (t & 7));
            const int str = isng ? 32 : 8;
            float4 acc = make_float4(0.f, 0.f, 0.f, 0.f);
            #pragma unroll
            for (int s = 0; s < 16; s++) {
                const float4 v = base[s * str];
                acc.x = fmaf(e[s], v.x, acc.x);
                acc.y = fmaf(e[s], v.y, acc.y);
                acc.z = fmaf(e[s], v.z, acc.z);
                acc.w = fmaf(e[s], v.w, acc.w);
            }
            acc.x *= rinv; acc.y *= rinv; acc.z *= rinv; acc.w *= rinv;
            if (isng) {
                // agg f16-packed into the h' slot (K3 overwrites with f32 h')
                union { __half2 h[2]; float2 f; } u;
                u.h[0] = __floats2half2_rn(acc.x, acc.y);
                u.h[1] = __floats2half2_rn(acc.z, acc.w);
                ((float2*)(out + (size_t)n * 160 + 64))[t] = u.f;
            } else if (t < 40) {
                *(float4*)(out + (size_t)n * 160 + 128 + ((t & 7) << 2)) = acc;
            }
        }
        if (q == 3) asm volatile("s_waitcnt vmcnt(0)" ::: "memory");
        BAR();   // BAR2
    }
}

// K3: out[:,0:64) = input @ W ; out[:,64:128) = agg(f16,in out) @ W2 (in-place)
__global__ __launch_bounds__(256, 2)
void post_gemm(const float* __restrict__ input,
               const float* __restrict__ W,
               const float* __restrict__ W2,
               float* __restrict__ out, int N) {
    const int t = threadIdx.x;
    const int NB = (N + 63) >> 6;
    const bool second = ((int)blockIdx.x >= NB);
    const int rbase = (second ? blockIdx.x - NB : blockIdx.x) << 6;
    const int nrows = min(64, N - rbase);
    const float* Wsrc = second ? W2 : W;
    const int dstcol = second ? 64 : 0;

    __shared__ __align__(16) float sS[64 * 128];   // [r][k] 32KB
    __shared__ __align__(16) float sW[128 * 64];   // [k][c] 32KB

    #pragma unroll
    for (int i = 0; i < 8; i++) {
        const int idx = t + i * 256;
        ((float4*)sW)[idx] = ((const float4*)Wsrc)[idx];
    }
    if (!second) {
        #pragma unroll
        for (int i = 0; i < 8; i++) {
            const int idx = t + i * 256;           // (r = idx>>5, j = idx&31)
            const int r = idx >> 5;
            float4 v = make_float4(0.f, 0.f, 0.f, 0.f);
            if (r < nrows)
                v = ((const float4*)(input + (size_t)(rbase + r) * 128))[idx & 31];
            ((float4*)sS)[idx] = v;
        }
    } else {
        #pragma unroll
        for (int i = 0; i < 8; i++) {
            const int idx = t + i * 256;
            const int r = idx >> 5, j = idx & 31;  // j-th group of 4 halves
            float4 v = make_float4(0.f, 0.f, 0.f, 0.f);
            if (r < nrows) {
                union { float2 f; __half2 h[2]; } u;
                u.f = ((const float2*)(out + (size_t)(rbase + r) * 160 + 64))[j];
                const float2 lo = __half22float2(u.h[0]);
                const float2 hi = __half22float2(u.h[1]);
                v = make_float4(lo.x, lo.y, hi.x, hi.y);
            }
            ((float4*)sS)[idx] = v;
        }
    }
    __syncthreads();

    const int r0 = ((t >> 4) & 15) << 2, c0 = (t & 15) << 2;
    float4 acc0 = make_float4(0,0,0,0), acc1 = acc0, acc2 = acc0, acc3 = acc0;
    #pragma unroll 2
    for (int k4 = 0; k4 < 32; k4++) {
        const int k = k4 << 2;
        const float4 a0 = *(const float4*)(sS + (r0 + 0) * 128 + k);
        const float4 a1 = *(const float4*)(sS + (r0 + 1) * 128 + k);
        const float4 a2 = *(const float4*)(sS + (r0 + 2) * 128 + k);
        const float4 a3 = *(const float4*)(sS + (r0 + 3) * 128 + k);
        const float4 w0 = *(const float4*)(sW + (k + 0) * 64 + c0);
        const float4 w1 = *(const float4*)(sW + (k + 1) * 64 + c0);
        const float4 w2 = *(const float4*)(sW + (k + 2) * 64 + c0);
        const float4 w3 = *(const float4*)(sW + (k + 3) * 64 + c0);
        #define MADROW(ACC, A)                                              \
            ACC.x = fmaf(A.x, w0.x, ACC.x); ACC.y = fmaf(A.x, w0.y, ACC.y); \
            ACC.z = fmaf(A.x, w0.z, ACC.z); ACC.w = fmaf(A.x, w0.w, ACC.w); \
            ACC.x = fmaf(A.y, w1.x, ACC.x); ACC.y = fmaf(A.y, w1.y, ACC.y); \
            ACC.z = fmaf(A.y, w1.z, ACC.z); ACC.w = fmaf(A.y, w1.w, ACC.w); \
            ACC.x = fmaf(A.z, w2.x, ACC.x); ACC.y = fmaf(A.z, w2.y, ACC.y); \
            ACC.z = fmaf(A.z, w2.z, ACC.z); ACC.w = fmaf(A.z, w2.w, ACC.w); \
            ACC.x = fmaf(A.w, w3.x, ACC.x); ACC.y = fmaf(A.w, w3.y, ACC.y); \
            ACC.z = fmaf(A.w, w3.z, ACC.z); ACC.w = fmaf(A.w, w3.w, ACC.w);
        MADROW(acc0, a0) MADROW(acc1, a1) MADROW(acc2, a2) MADROW(acc3, a3)
        #undef MADROW
    }
    if (r0 + 0 < nrows) *(float4*)(out + (size_t)(rbase + r0 + 0) * 160 + dstcol + c0) = acc0;
    if (r0 + 1 < nrows) *(float4*)(out + (size_t)(rbase + r0 + 1) * 160 + dstcol + c0) = acc1;
    if (r0 + 2 < nrows) *(float4*)(out + (size_t)(rbase + r0 + 2) * 160 + dstcol + c0) = acc2;
    if (r0 + 3 < nrows) *(float4*)(out + (size_t)(rbase + r0 + 3) * 160 + dstcol + c0) = acc3;
}

extern "C" void kernel_launch(void* const* d_in, const int* in_sizes, int n_in,
                              void* d_out, int out_size, void* d_ws, size_t ws_size,
                              hipStream_t stream) {
    const float* input = (const float*)d_in[0];
    const float* neigh = (const float*)d_in[1];
    const float* edge  = (const float*)d_in[2];
    const float* W     = (const float*)d_in[3];
    const float* W2    = (const float*)d_in[4];
    const float* a     = (const float*)d_in[5];
    float* ws = (float*)d_ws;
    float* out = (float*)d_out;

    const int N = in_sizes[0] / 128;   // 50000
    const int NB = (N + 63) >> 6;      // 782

    prep_kernel<<<1, 256, 0, stream>>>(W, W2, a, ws);
    gat_attn<<<1792, 256, 0, stream>>>(input, neigh, edge, ws, out, N);
    post_gemm<<<2 * NB, 256, 0, stream>>>(input, W, W2, out, N);
}

// Round 6
// 661.915 us; speedup vs baseline: 1.2649x; 1.0466x over previous
//
#include <hip/hip_runtime.h>
#include <hip/hip_fp16.h>

// EdgeEmbAttentionAggregator — R5 (resubmit R6; R5 bench failed on GPU
// acquisition — no counters). Pair-per-iteration attention pass.
// Algebra: score_s = sx + ng_s·w2a + ee_s·a_e  (sx = in·(W@a_x), w2a = W2@a_n)
// h' = agg@W2 (agg stored f16 in out h' slot, overwritten by post_gemm).
// R5 vs R4: 2 nodes/iter (1 barrier/node), in·Wa removed from Phase B
// (wave 3 computes sx once per node), Phase C parallel across all 4 waves
// (wave w -> node w&1, column-half w>>1).

#define BAR() do {                                              \
    asm volatile("s_waitcnt lgkmcnt(0)" ::: "memory");          \
    __builtin_amdgcn_s_barrier();                               \
    asm volatile("" ::: "memory");                               \
} while (0)

#define GLDS16(gp, lp) __builtin_amdgcn_global_load_lds(                     \
    (const __attribute__((address_space(1))) void*)(gp),                     \
    (__attribute__((address_space(3))) void*)(lp), 16, 0, 0)
#define GLDS4(gp, lp)  __builtin_amdgcn_global_load_lds(                     \
    (const __attribute__((address_space(1))) void*)(gp),                     \
    (__attribute__((address_space(3))) void*)(lp), 4, 0, 0)

__device__ __forceinline__ float dot4(float4 a, float4 b) {
    return fmaf(a.x, b.x, fmaf(a.y, b.y, fmaf(a.z, b.z, a.w * b.w)));
}

// ws layout (fp32): [0:128) w2a=W2@a_n ; [128:288) a copy ; [288:416) Wa=W@a_x
__global__ __launch_bounds__(256)
void prep_kernel(const float* __restrict__ W,
                 const float* __restrict__ W2,
                 const float* __restrict__ a,
                 float* __restrict__ ws) {
    const int t = threadIdx.x;
    __shared__ float s_a[160];
    if (t < 160) { float v = a[t]; s_a[t] = v; ws[128 + t] = v; }
    __syncthreads();
    if (t < 128) {
        float p = 0.f, pw = 0.f;
        #pragma unroll
        for (int d = 0; d < 64; d++) {
            p  = fmaf(W2[t * 64 + d], s_a[64 + d], p);
            pw = fmaf(W [t * 64 + d], s_a[d],      pw);
        }
        ws[t] = p;
        ws[288 + t] = pw;
    }
}

__device__ __forceinline__ void dma_node(const float* __restrict__ neigh,
                                         const float* __restrict__ edge,
                                         const float* __restrict__ input,
                                         int node, int lane,
                                         float* ng, float* ee, float* inb) {
    const float* gn = neigh + (size_t)node * 2048;
    #pragma unroll
    for (int i = 0; i < 8; i++) GLDS16(gn + i * 256 + lane * 4, ng + i * 256);
    const float* ge = edge + (size_t)node * 512;
    #pragma unroll
    for (int i = 0; i < 2; i++) GLDS16(ge + i * 256 + lane * 4, ee + i * 256);
    const float* gi = input + (size_t)node * 128;
    #pragma unroll
    for (int i = 0; i < 2; i++) GLDS4(gi + i * 64 + lane, inb + i * 64);
}

__global__ __launch_bounds__(256, 3)
void gat_attn(const float* __restrict__ input,
              const float* __restrict__ neigh,
              const float* __restrict__ edge,
              const float* __restrict__ ws,
              float* __restrict__ out, int N) {
    const int t = threadIdx.x;
    const int q = t >> 6;
    const int lane = t & 63;

    __shared__ __align__(16) float s_w2a[128];
    __shared__ __align__(16) float s_wa[128];
    __shared__ __align__(16) float s_ae[32];
    __shared__ __align__(16) float s_ng[2][2][2048];  // [pairbuf][node] 16x128
    __shared__ __align__(16) float s_ee[2][2][512];   // 16x32
    __shared__ __align__(16) float s_in[2][2][128];
    __shared__ __align__(16) float s_sc[32];          // [node*16 + s]
    __shared__ float s_sx[2];

    if (t < 128) { s_w2a[t] = ws[t]; s_wa[t] = ws[288 + t]; }
    else if (t < 160) s_ae[t - 128] = ws[128 + t];    // ws[256:288) = a_e

    const int P = (N + 1) >> 1;       // node pairs
    const int stride = gridDim.x;
    int p = blockIdx.x;
    int cur = 0;

    // ---- prologue: wave 3 DMAs pair p into buf 0
    if (q == 3 && p < P) {
        dma_node(neigh, edge, input, 2 * p, lane,
                 s_ng[0][0], s_ee[0][0], s_in[0][0]);
        dma_node(neigh, edge, input, min(2 * p + 1, N - 1), lane,
                 s_ng[0][1], s_ee[0][1], s_in[0][1]);
        asm volatile("s_waitcnt vmcnt(0)" ::: "memory");
    }
    BAR();   // also covers s_w2a/s_wa/s_ae

    for (; p < P; p += stride, cur ^= 1) {
        const int nA = 2 * p;
        const int nB = min(2 * p + 1, N - 1);
        const int pn = p + stride;

        // ---- wave 3: issue DMA for next pair, then sx for current pair
        if (q == 3) {
            if (pn < P) {
                dma_node(neigh, edge, input, 2 * pn, lane,
                         s_ng[cur ^ 1][0], s_ee[cur ^ 1][0], s_in[cur ^ 1][0]);
                dma_node(neigh, edge, input, min(2 * pn + 1, N - 1), lane,
                         s_ng[cur ^ 1][1], s_ee[cur ^ 1][1], s_in[cur ^ 1][1]);
            }
            const float2 ia = ((const float2*)s_in[cur][0])[lane];
            const float2 ib = ((const float2*)s_in[cur][1])[lane];
            const float2 w  = ((const float2*)s_wa)[lane];
            float pa = fmaf(ia.x, w.x, ia.y * w.y);
            float pb = fmaf(ib.x, w.x, ib.y * w.y);
            #pragma unroll
            for (int off = 32; off; off >>= 1) {
                pa += __shfl_xor(pa, off, 64);
                pb += __shfl_xor(pb, off, 64);
            }
            if (lane == 0) { s_sx[0] = pa; s_sx[1] = pb; }
        }

        // ---- Phase B: pre-scores (no sx), 32 rows x 8 lanes
        {
            const int r = t >> 3, g = t & 7;       // r: [node*16 + s]
            const int node = r >> 4, s = r & 15;
            const float4* ng4  = (const float4*)(s_ng[cur][node] + s * 128);
            const float4* w2a4 = (const float4*)s_w2a;
            float pp = dot4(ng4[g],      w2a4[g])
                     + dot4(ng4[g + 8],  w2a4[g + 8])
                     + dot4(ng4[g + 16], w2a4[g + 16])
                     + dot4(ng4[g + 24], w2a4[g + 24]);
            pp += dot4(((const float4*)(s_ee[cur][node] + s * 32))[g],
                       ((const float4*)s_ae)[g]);
            pp += __shfl_down(pp, 4, 8);
            pp += __shfl_down(pp, 2, 8);
            pp += __shfl_down(pp, 1, 8);
            if (g == 0) s_sc[r] = pp;
        }
        BAR();   // BAR1

        // ---- Phase C: wave q -> node q&1, column-half q>>1
        {
            const int node = q & 1, half = q >> 1;
            const int n = node ? nB : nA;
            const float sx = s_sx[node];
            float e[16];
            #pragma unroll
            for (int j = 0; j < 4; j++) {
                float4 v = ((const float4*)s_sc)[node * 4 + j];
                v.x += sx; v.y += sx; v.z += sx; v.w += sx;
                e[4*j+0] = v.x > 0.f ? v.x : 0.8f * v.x;
                e[4*j+1] = v.y > 0.f ? v.y : 0.8f * v.y;
                e[4*j+2] = v.z > 0.f ? v.z : 0.8f * v.z;
                e[4*j+3] = v.w > 0.f ? v.w : 0.8f * v.w;
            }
            float m[8];
            #pragma unroll
            for (int i = 0; i < 8; i++) m[i] = fmaxf(e[i], e[i + 8]);
            #pragma unroll
            for (int i = 0; i < 4; i++) m[i] = fmaxf(m[i], m[i + 4]);
            const float mx = fmaxf(fmaxf(m[0], m[2]), fmaxf(m[1], m[3]));
            #pragma unroll
            for (int s = 0; s < 16; s++) e[s] = __expf(e[s] - mx);
            float sm[8];
            #pragma unroll
            for (int i = 0; i < 8; i++) sm[i] = e[i] + e[i + 8];
            #pragma unroll
            for (int i = 0; i < 4; i++) sm[i] = sm[i] + sm[i + 4];
            const float rinv = 1.0f / ((sm[0] + sm[2]) + (sm[1] + sm[3]));

            if (lane < 20) {
                const int fc = half * 20 + lane;   // f4-column 0..39
                if (fc < 32) {                      // neigh cols -> agg (f16)
                    const float4* col = (const float4*)s_ng[cur][node] + fc;
                    float4 acc = make_float4(0.f, 0.f, 0.f, 0.f);
                    #pragma unroll
                    for (int s = 0; s < 16; s++) {
                        const float4 v = col[s * 32];
                        acc.x = fmaf(e[s], v.x, acc.x);
                        acc.y = fmaf(e[s], v.y, acc.y);
                        acc.z = fmaf(e[s], v.z, acc.z);
                        acc.w = fmaf(e[s], v.w, acc.w);
                    }
                    union { __half2 h[2]; float2 f; } u;
                    u.h[0] = __floats2half2_rn(acc.x * rinv, acc.y * rinv);
                    u.h[1] = __floats2half2_rn(acc.z * rinv, acc.w * rinv);
                    ((float2*)(out + (size_t)n * 160 + 64))[fc] = u.f;
                } else {                            // edge cols -> h_edge (f32)
                    const int ec = fc - 32;
                    const float4* col = (const float4*)s_ee[cur][node] + ec;
                    float4 acc = make_float4(0.f, 0.f, 0.f, 0.f);
                    #pragma unroll
                    for (int s = 0; s < 16; s++) {
                        const float4 v = col[s * 8];
                        acc.x = fmaf(e[s], v.x, acc.x);
                        acc.y = fmaf(e[s], v.y, acc.y);
                        acc.z = fmaf(e[s], v.z, acc.z);
                        acc.w = fmaf(e[s], v.w, acc.w);
                    }
                    acc.x *= rinv; acc.y *= rinv; acc.z *= rinv; acc.w *= rinv;
                    *(float4*)(out + (size_t)n * 160 + 128 + (ec << 2)) = acc;
                }
            }
        }
        // wave 3's DMA for pair pn must land before next iter reads cur^1
        if (q == 3) asm volatile("s_waitcnt vmcnt(0)" ::: "memory");
        BAR();   // BAR2
    }
}

// K3: out[:,0:64) = input @ W ; out[:,64:128) = agg(f16,in out) @ W2 (in-place)
__global__ __launch_bounds__(256, 2)
void post_gemm(const float* __restrict__ input,
               const float* __restrict__ W,
               const float* __restrict__ W2,
               float* __restrict__ out, int N) {
    const int t = threadIdx.x;
    const int NB = (N + 63) >> 6;
    const bool second = ((int)blockIdx.x >= NB);
    const int rbase = (second ? blockIdx.x - NB : blockIdx.x) << 6;
    const int nrows = min(64, N - rbase);
    const float* Wsrc = second ? W2 : W;
    const int dstcol = second ? 64 : 0;

    __shared__ __align__(16) float sS[64 * 128];   // [r][k] 32KB
    __shared__ __align__(16) float sW[128 * 64];   // [k][c] 32KB

    #pragma unroll
    for (int i = 0; i < 8; i++) {
        const int idx = t + i * 256;
        ((float4*)sW)[idx] = ((const float4*)Wsrc)[idx];
    }
    if (!second) {
        #pragma unroll
        for (int i = 0; i < 8; i++) {
            const int idx = t + i * 256;
            const int r = idx >> 5;
            float4 v = make_float4(0.f, 0.f, 0.f, 0.f);
            if (r < nrows)
                v = ((const float4*)(input + (size_t)(rbase + r) * 128))[idx & 31];
            ((float4*)sS)[idx] = v;
        }
    } else {
        #pragma unroll
        for (int i = 0; i < 8; i++) {
            const int idx = t + i * 256;
            const int r = idx >> 5, j = idx & 31;
            float4 v = make_float4(0.f, 0.f, 0.f, 0.f);
            if (r < nrows) {
                union { float2 f; __half2 h[2]; } u;
                u.f = ((const float2*)(out + (size_t)(rbase + r) * 160 + 64))[j];
                const float2 lo = __half22float2(u.h[0]);
                const float2 hi = __half22float2(u.h[1]);
                v = make_float4(lo.x, lo.y, hi.x, hi.y);
            }
            ((float4*)sS)[idx] = v;
        }
    }
    __syncthreads();

    const int r0 = ((t >> 4) & 15) << 2, c0 = (t & 15) << 2;
    float4 acc0 = make_float4(0,0,0,0), acc1 = acc0, acc2 = acc0, acc3 = acc0;
    #pragma unroll 2
    for (int k4 = 0; k4 < 32; k4++) {
        const int k = k4 << 2;
        const float4 a0 = *(const float4*)(sS + (r0 + 0) * 128 + k);
        const float4 a1 = *(const float4*)(sS + (r0 + 1) * 128 + k);
        const float4 a2 = *(const float4*)(sS + (r0 + 2) * 128 + k);
        const float4 a3 = *(const float4*)(sS + (r0 + 3) * 128 + k);
        const float4 w0 = *(const float4*)(sW + (k + 0) * 64 + c0);
        const float4 w1 = *(const float4*)(sW + (k + 1) * 64 + c0);
        const float4 w2 = *(const float4*)(sW + (k + 2) * 64 + c0);
        const float4 w3 = *(const float4*)(sW + (k + 3) * 64 + c0);
        #define MADROW(ACC, A)                                              \
            ACC.x = fmaf(A.x, w0.x, ACC.x); ACC.y = fmaf(A.x, w0.y, ACC.y); \
            ACC.z = fmaf(A.x, w0.z, ACC.z); ACC.w = fmaf(A.x, w0.w, ACC.w); \
            ACC.x = fmaf(A.y, w1.x, ACC.x); ACC.y = fmaf(A.y, w1.y, ACC.y); \
            ACC.z = fmaf(A.y, w1.z, ACC.z); ACC.w = fmaf(A.y, w1.w, ACC.w); \
            ACC.x = fmaf(A.z, w2.x, ACC.x); ACC.y = fmaf(A.z, w2.y, ACC.y); \
            ACC.z = fmaf(A.z, w2.z, ACC.z); ACC.w = fmaf(A.z, w2.w, ACC.w); \
            ACC.x = fmaf(A.w, w3.x, ACC.x); ACC.y = fmaf(A.w, w3.y, ACC.y); \
            ACC.z = fmaf(A.w, w3.z, ACC.z); ACC.w = fmaf(A.w, w3.w, ACC.w);
        MADROW(acc0, a0) MADROW(acc1, a1) MADROW(acc2, a2) MADROW(acc3, a3)
        #undef MADROW
    }
    if (r0 + 0 < nrows) *(float4*)(out + (size_t)(rbase + r0 + 0) * 160 + dstcol + c0) = acc0;
    if (r0 + 1 < nrows) *(float4*)(out + (size_t)(rbase + r0 + 1) * 160 + dstcol + c0) = acc1;
    if (r0 + 2 < nrows) *(float4*)(out + (size_t)(rbase + r0 + 2) * 160 + dstcol + c0) = acc2;
    if (r0 + 3 < nrows) *(float4*)(out + (size_t)(rbase + r0 + 3) * 160 + dstcol + c0) = acc3;
}

extern "C" void kernel_launch(void* const* d_in, const int* in_sizes, int n_in,
                              void* d_out, int out_size, void* d_ws, size_t ws_size,
                              hipStream_t stream) {
    const float* input = (const float*)d_in[0];
    const float* neigh = (const float*)d_in[1];
    const float* edge  = (const float*)d_in[2];
    const float* W     = (const float*)d_in[3];
    const float* W2    = (const float*)d_in[4];
    const float* a     = (const float*)d_in[5];
    float* ws = (float*)d_ws;
    float* out = (float*)d_out;

    const int N = in_sizes[0] / 128;   // 50000
    const int NB = (N + 63) >> 6;      // 782

    prep_kernel<<<1, 256, 0, stream>>>(W, W2, a, ws);
    gat_attn<<<768, 256, 0, stream>>>(input, neigh, edge, ws, out, N);
    post_gemm<<<2 * NB, 256, 0, stream>>>(input, W, W2, out, N);
}